// Round 19
// baseline (1015.814 us; speedup 1.0000x reference)
//
#include <hip/hip_runtime.h>
#include <hip/hip_bf16.h>
#include <stdint.h>

// Problem constants (from reference)
#define B_      8
#define N_      16384
#define NPOINT  512
#define KNN_    16
#define C_      16

// Exact IEEE f32 ops — bit-match the numpy (ref=np) lowering:
//   p2/s2 : np.sum(v*v,-1)  -> pairwise small-n ASCENDING:  (x2+y2)+z2, no FMA
//   FPS d : np.sum(dd*dd,-1)-> ASCENDING:  (dx2+dy2)+dz2, no FMA
//   dot   : np.einsum unopt -> sum_of_products_contig_two remainder switch,
//           DESCENDING fallthrough:  ((sz*pz) + sy*py) + sx*px, no FMA
//   dist  : (s2 + p2) - 2*dot   elementwise, no FMA
__device__ __forceinline__ float fmulrn(float a, float b){ return __fmul_rn(a,b); }
__device__ __forceinline__ float faddrn(float a, float b){ return __fadd_rn(a,b); }
__device__ __forceinline__ float fsubrn(float a, float b){ return __fsub_rn(a,b); }

// ---------------------------------------------------------------------------
// DPP reductions (VALU pipe, zero LDS ops).
// ---------------------------------------------------------------------------
__device__ __forceinline__ uint32_t umax_(uint32_t a, uint32_t b){ return a > b ? a : b; }

__device__ __forceinline__ uint32_t row16_max(uint32_t x){
    uint32_t t;
    t = (uint32_t)__builtin_amdgcn_update_dpp((int)x, (int)x, 0x111, 0xf, 0xf, false); x = umax_(x, t);
    t = (uint32_t)__builtin_amdgcn_update_dpp((int)x, (int)x, 0x112, 0xf, 0xf, false); x = umax_(x, t);
    t = (uint32_t)__builtin_amdgcn_update_dpp((int)x, (int)x, 0x114, 0xf, 0xf, false); x = umax_(x, t);
    t = (uint32_t)__builtin_amdgcn_update_dpp((int)x, (int)x, 0x118, 0xf, 0xf, false); x = umax_(x, t);
    return x;
}

__device__ __forceinline__ uint32_t wave_max_uniform(uint32_t x){
    x = row16_max(x);
    uint32_t a = (uint32_t)__builtin_amdgcn_readlane((int)x, 15);
    uint32_t b = (uint32_t)__builtin_amdgcn_readlane((int)x, 31);
    uint32_t c = (uint32_t)__builtin_amdgcn_readlane((int)x, 47);
    uint32_t d = (uint32_t)__builtin_amdgcn_readlane((int)x, 63);
    return umax_(umax_(a, b), umax_(c, d));
}

// u64 max across each quad (lanes 4k..4k+3): 2 quad_perm DPP steps.
__device__ __forceinline__ unsigned long long quad_max_u64(unsigned long long k){
    uint32_t lo = (uint32_t)k, hi = (uint32_t)(k >> 32);
    {   // quad_perm [1,0,3,2] = 0xB1
        uint32_t olo = (uint32_t)__builtin_amdgcn_update_dpp((int)lo, (int)lo, 0xB1, 0xf, 0xf, false);
        uint32_t ohi = (uint32_t)__builtin_amdgcn_update_dpp((int)hi, (int)hi, 0xB1, 0xf, 0xf, false);
        bool take = (ohi > hi) || (ohi == hi && olo > lo);
        hi = take ? ohi : hi; lo = take ? olo : lo;
    }
    {   // quad_perm [2,3,0,1] = 0x4E
        uint32_t olo = (uint32_t)__builtin_amdgcn_update_dpp((int)lo, (int)lo, 0x4E, 0xf, 0xf, false);
        uint32_t ohi = (uint32_t)__builtin_amdgcn_update_dpp((int)hi, (int)hi, 0x4E, 0xf, 0xf, false);
        bool take = (ohi > hi) || (ohi == hi && olo > lo);
        hi = take ? ohi : hi; lo = take ? olo : lo;
    }
    return ((unsigned long long)hi << 32) | lo;
}

// ---------------------------------------------------------------------------
// Kernel 1: pack {x, y, z, p2} per point.  p2 = (x*x + y*y) + z*z  (ascending).
// ---------------------------------------------------------------------------
__global__ void prep_kernel(const float* __restrict__ x, float4* __restrict__ pts){
    int i = blockIdx.x * blockDim.x + threadIdx.x;   // 0 .. B_*N_-1
    if (i >= B_ * N_) return;
    const float4* x4 = (const float4*)x;             // x row = 16 floats = 4 float4
    float4 q = x4[(size_t)i * 4];                    // channels 0..3: x,y,z,c3
    float p2 = faddrn(faddrn(fmulrn(q.x,q.x), fmulrn(q.y,q.y)), fmulrn(q.z,q.z));
    pts[i] = make_float4(q.x, q.y, q.z, p2);
}

// ---------------------------------------------------------------------------
// Kernel 1b: zero the mailbox (every launch — graph replays reuse ws).
// ---------------------------------------------------------------------------
#define FPS_NB   4
#define MBOX_N   (B_ * NPOINT * FPS_NB)    // 16384 u64 = 128 KiB
__global__ void zero_part_kernel(unsigned long long* __restrict__ part){
    int i = blockIdx.x * blockDim.x + threadIdx.x;
    if (i < MBOX_N) part[i] = 0ULL;
}

// ---------------------------------------------------------------------------
// Kernel 2: multi-block FPS — BYTE-IDENTICAL to R18 (passed: 786-790us).
// 4 blocks x 1024 thr x 4 slots, 4-entry block mailbox, DPP reduces, u64
// keys {val_bits, ~idx}, nonzero==ready, re-zeroed per launch, bounded spin
// bails out, defensive index clamp.
// ---------------------------------------------------------------------------
#define FPS_T    1024
#define FPS_NW   (FPS_T/64)          // 16 waves
#define SLICE    (N_ / FPS_NB)       // 4096 points per block
#define FOR_S4(F) F(0) F(1) F(2) F(3)

__global__ void __launch_bounds__(FPS_T)
fps_kernel_mb(const float4* __restrict__ pts, float4* __restrict__ s_out,
              unsigned long long* __restrict__ part){
    __shared__ float2   xy[SLICE];              // 32 KiB slice of (x,y)
    __shared__ uint32_t red_v[2][FPS_NW];
    __shared__ uint32_t red_i[2][FPS_NW];

    const int b    = blockIdx.x & 7;            // batch (same XCD per batch)
    const int blk  = blockIdx.x >> 3;           // sub-block 0..FPS_NB-1
    const int tid  = threadIdx.x;
    const int lane = tid & 63;
    const int wv   = tid >> 6;
    const int base = blk * SLICE;               // global offset of this slice
    const float4* P = pts + (size_t)b * N_;
    unsigned long long* mbox = part + ((size_t)b * NPOINT) * FPS_NB;

#define DECL_S(s) float z##s, md##s;
    FOR_S4(DECL_S)
#undef DECL_S

#define INIT_S(s) { float4 q = P[base + (s) * FPS_T + tid]; \
        xy[(s) * FPS_T + tid] = make_float2(q.x, q.y); \
        z##s = q.z; md##s = 1e10f; }
    FOR_S4(INIT_S)
#undef INIT_S

    float lx, ly, lz;
    {
        float4 q0 = P[0];                       // seed = index 0
        lx = q0.x; ly = q0.y; lz = q0.z;
        if (blk == 0 && tid == 0) s_out[(size_t)b * NPOINT + 0] = q0;
    }
    __syncthreads();                            // staging visible

    for (int it = 1; it < NPOINT; ++it){
        float    bv = -1.0f;                    // all min_d >= 0
        uint32_t bi = 0;                        // GLOBAL point index
        // slots ascend in global index -> strict > keeps first occurrence
#define DO_S(s) { \
        float2 c = xy[(s) * FPS_T + tid]; \
        float dx = fsubrn(c.x, lx); \
        float dy = fsubrn(c.y, ly); \
        float dz = fsubrn(z##s, lz); \
        float d  = faddrn(faddrn(fmulrn(dx,dx), fmulrn(dy,dy)), fmulrn(dz,dz)); \
        md##s = fminf(md##s, d); \
        if (md##s > bv){ bv = md##s; bi = (uint32_t)(base + (s) * FPS_T + tid); } }
        FOR_S4(DO_S)
#undef DO_S

        // ---- in-block reduce (DPP, uniform) ----
        uint32_t vb    = __float_as_uint(bv);
        uint32_t gmaxw = wave_max_uniform(vb);
        uint32_t gidxw = wave_max_uniform((vb == gmaxw) ? ~bi : 0u);
        const int par = it & 1;
        if (lane == 0){ red_v[par][wv] = gmaxw; red_i[par][wv] = gidxw; }
        __syncthreads();
        uint32_t rv = red_v[par][lane & 15];
        uint32_t ri = red_i[par][lane & 15];
        uint32_t gv = (uint32_t)__builtin_amdgcn_readlane((int)row16_max(rv), 15);
        uint32_t gn = (uint32_t)__builtin_amdgcn_readlane(
                          (int)row16_max((rv == gv) ? ri : 0u), 15);
        unsigned long long kblk = ((unsigned long long)gv << 32) | gn; // never 0

        // ---- publish + poll mailbox (agent scope, L1-bypassing) ----
        unsigned long long* slotp = mbox + (size_t)it * FPS_NB;
        if (tid == 0)
            __hip_atomic_store(&slotp[blk], kblk, __ATOMIC_RELAXED,
                               __HIP_MEMORY_SCOPE_AGENT);
        unsigned long long v = 0;
        int guard = 0;
        for (;;){
            if (v == 0)
                v = __hip_atomic_load(&slotp[lane & 3], __ATOMIC_RELAXED,
                                      __HIP_MEMORY_SCOPE_AGENT);
            if (__all(v != 0ULL)) break;
            if (++guard > (1 << 20)) return;    // bail: fail fast, never hang
        }
        unsigned long long kmax = quad_max_u64(v);   // global winner, all lanes
        uint32_t gi  = ~((uint32_t)kmax);
        uint32_t giu = (uint32_t)__builtin_amdgcn_readfirstlane((int)gi);
        giu &= (uint32_t)(N_ - 1);              // defensive: in-bounds by design
        float4 q = P[giu];                      // uniform -> scalar load path
        lx = q.x; ly = q.y; lz = q.z;
        if (blk == 0 && tid == 0) s_out[(size_t)b * NPOINT + it] = q;
    }
}

// ---------------------------------------------------------------------------
// Kernel 3: exact 16-NN, LDS-tiled, TWO WAVES PER ROW (R19 change).
// R18 analysis: per-SIMD issue floor ~80us vs 210 observed -> stall-bound,
// and occupancy is grid-limited (4096 row-waves = 4/SIMD). Split each row's
// scan across 2 waves (even wave: groups 0-7 of each tile; odd: 8-15) ->
// 8192 waves = 8/SIMD, double the latency-hiding pool, same issue work.
// Each wave merges its own top-16 (proven 16-round merge, capturing full
// u64 keys), writes them to LDS; the pair then merges 32 unique keys
// (disjoint candidate ranges; u64 keys embed idx -> total order, exactness
// trivially preserved). Even wave writes the output row.
// waves_per_eu removed: loop-carried v0..v15 (~52 VGPR) fit the allocator's
// max-occupancy budget (R5-R10 lesson: loop-carried scalars stay resident).
// DEFENSIVE: myidx &= N_-1.
// ---------------------------------------------------------------------------
#define KT       1024                 // tile points
#define KNN_T    512                  // threads: 8 waves = 4 rows x 2 waves

__global__ void __launch_bounds__(KNN_T)
knn_kernel(const float* __restrict__ x,
           const float4* __restrict__ pts,
           const float4* __restrict__ s_arr,
           float* __restrict__ out){
    __shared__ float4 tile[KT];                          // 16 KiB
    __shared__ unsigned long long km[8][KNN_];           // 1 KiB: per-wave top-16

    const int wv   = threadIdx.x >> 6;          // wave 0..7
    const int lane = threadIdx.x & 63;
    const int row  = wv >> 1;                   // row-in-block 0..3
    const int half = wv & 1;                    // 0: groups 0-7, 1: groups 8-15
    const int blk  = blockIdx.x;                // 0 .. B_*NPOINT/4 - 1
    const int b    = blk >> 7;                  // 128 blocks per batch
    const int p    = ((blk & 127) << 2) | row;

    const float4 s = s_arr[(size_t)b * NPOINT + p];
    const float sx = s.x, sy = s.y, sz = s.z, s2 = s.w;
    const float4* P = pts + (size_t)b * N_;

#define FOR_V(F) F(0) F(1) F(2) F(3) F(4) F(5) F(6) F(7) \
                 F(8) F(9) F(10) F(11) F(12) F(13) F(14) F(15)
#define DECLV(t) unsigned long long v##t = ~0ULL;
    FOR_V(DECLV)
#undef DECLV

#define PROC(q, n) { \
        float dot = faddrn(faddrn(fmulrn(sz, (q).z), fmulrn(sy, (q).y)), fmulrn(sx, (q).x)); \
        float d = fsubrn(faddrn(s2, (q).w), fmulrn(2.0f, dot)); \
        uint32_t bits = __float_as_uint(d); \
        uint32_t key  = bits ^ (((uint32_t)((int32_t)bits >> 31)) | 0x80000000u); \
        unsigned long long c = ((unsigned long long)key << 32) | (uint32_t)(n); \
        if (c < v15){ \
            bool lt0=c<v0,  lt1=c<v1,  lt2=c<v2,  lt3=c<v3; \
            bool lt4=c<v4,  lt5=c<v5,  lt6=c<v6,  lt7=c<v7; \
            bool lt8=c<v8,  lt9=c<v9,  lt10=c<v10, lt11=c<v11; \
            bool lt12=c<v12, lt13=c<v13, lt14=c<v14; \
            v15 = lt14 ? v14 : c; \
            v14 = lt14 ? (lt13 ? v13 : c) : v14; \
            v13 = lt13 ? (lt12 ? v12 : c) : v13; \
            v12 = lt12 ? (lt11 ? v11 : c) : v12; \
            v11 = lt11 ? (lt10 ? v10 : c) : v11; \
            v10 = lt10 ? (lt9  ? v9  : c) : v10; \
            v9  = lt9  ? (lt8  ? v8  : c) : v9;  \
            v8  = lt8  ? (lt7  ? v7  : c) : v8;  \
            v7  = lt7  ? (lt6  ? v6  : c) : v7;  \
            v6  = lt6  ? (lt5  ? v5  : c) : v6;  \
            v5  = lt5  ? (lt4  ? v4  : c) : v5;  \
            v4  = lt4  ? (lt3  ? v3  : c) : v4;  \
            v3  = lt3  ? (lt2  ? v2  : c) : v3;  \
            v2  = lt2  ? (lt1  ? v1  : c) : v2;  \
            v1  = lt1  ? (lt0  ? v0  : c) : v1;  \
            v0  = lt0  ? c : v0; \
        } }

    const int gbase = half << 3;                // first group this wave scans
    for (int t = 0; t < N_/KT; ++t){
        // stage tile: 512 threads x 2 float4 (coalesced, L2-resident source)
        float4 a0 = P[t*KT + threadIdx.x];
        float4 a1 = P[t*KT + threadIdx.x + KNN_T];
        __syncthreads();                        // prev scan done before overwrite
        tile[threadIdx.x]          = a0;
        tile[threadIdx.x + KNN_T]  = a1;
        __syncthreads();                        // tile visible
        // scan this wave's half: 8 groups, contiguous ds_read_b128 per lane
        #pragma unroll 4
        for (int g = gbase; g < gbase + 8; ++g){
            const int n = t*KT + (g << 6) + lane;
            float4 q = tile[(g << 6) + lane];
            PROC(q, n)
        }
    }
#undef PROC

    // ---- per-wave merge: 16 rounds, capture FULL key of round (lane>>2) ----
    unsigned long long mykey = ~0ULL;
    const int myr = lane >> 2;
    #pragma unroll 1
    for (int r = 0; r < KNN_; ++r){
        unsigned long long h = v0;
        unsigned long long g = h;
        #pragma unroll
        for (int off = 1; off < 64; off <<= 1){
            unsigned long long o = __shfl_xor(g, off, 64);
            if (o < g) g = o;
        }
        if (h == g){                          // unique winner (idx is unique)
            v0=v1; v1=v2; v2=v3; v3=v4; v4=v5; v5=v6; v6=v7; v7=v8;
            v8=v9; v9=v10; v10=v11; v11=v12; v12=v13; v13=v14; v14=v15;
            v15=~0ULL;
        }
        if (myr == r) mykey = g;              // full key of my output slot
    }
    if ((lane & 3) == 0) km[wv][myr] = mykey; // publish wave's sorted top-16
    __syncthreads();

    // ---- pair merge: 32 unique keys (both waves of the row compute) ----
    unsigned long long ka = ~0ULL;
    if (lane < 2*KNN_) ka = km[(row << 1) | (lane >> 4)][lane & 15];
    uint32_t myidx = 0;
    #pragma unroll 1
    for (int r = 0; r < KNN_; ++r){
        unsigned long long h = ka;
        unsigned long long g = h;
        #pragma unroll
        for (int off = 1; off < 64; off <<= 1){
            unsigned long long o = __shfl_xor(g, off, 64);
            if (o < g) g = o;
        }
        if (h == g) ka = ~0ULL;               // consume unique winner
        if (myr == r) myidx = (uint32_t)g;    // keep idx of my output slot
    }
    myidx &= (uint32_t)(N_ - 1);              // defensive: in-bounds by design

    // gather + write (even wave only): lane l -> neighbor l>>2, chans 4*(l&3)
    if (half == 0){
        const int c4 = lane & 3;
        const float4* X4 = (const float4*)x;
        float4 valq = X4[((size_t)b * N_ + myidx) * 4 + c4];
        float4* O4 = (float4*)out;
        O4[(((size_t)b * NPOINT + p) * KNN_ + myr) * 4 + c4] = valq;
    }
}

// ---------------------------------------------------------------------------
extern "C" void kernel_launch(void* const* d_in, const int* in_sizes, int n_in,
                              void* d_out, int out_size, void* d_ws, size_t ws_size,
                              hipStream_t stream) {
    const float* x = (const float*)d_in[0];
    float* out = (float*)d_out;

    // workspace: [pts: 2MB][s_arr: 64KB][mailbox: 128KB]
    const size_t pts_bytes  = (size_t)B_ * N_ * sizeof(float4);
    const size_t s_bytes    = (size_t)B_ * NPOINT * sizeof(float4);
    const size_t part_bytes = (size_t)MBOX_N * sizeof(unsigned long long);
    if (ws_size < pts_bytes + s_bytes + part_bytes) return;  // visible failure
    float4* pts   = (float4*)d_ws;
    float4* s_arr = (float4*)((char*)d_ws + pts_bytes);
    unsigned long long* part =
        (unsigned long long*)((char*)d_ws + pts_bytes + s_bytes);

    prep_kernel<<<(B_*N_ + 255)/256, 256, 0, stream>>>(x, pts);
    zero_part_kernel<<<(MBOX_N + 255)/256, 256, 0, stream>>>(part);
    fps_kernel_mb<<<B_*FPS_NB, FPS_T, 0, stream>>>(pts, s_arr, part);
    knn_kernel<<<(B_*NPOINT)/4, KNN_T, 0, stream>>>(x, pts, s_arr, out);
}